// Round 3
// baseline (242.165 us; speedup 1.0000x reference)
//
#include <hip/hip_runtime.h>

// SparseActivation: per row of D=2048 fp32, keep top K=204 by |x|, scale by D/K.
// One WAVE per row-pair: TWO rows per wave, all 16 float4 loads issued up-front
// so row B's HBM latency hides under row A's search (the kernel is
// latency-bound: VALUBusy 21%, HBM 30%, SIMD idle ~78% — round-1 counters).
// No integer unpack: counting compares use v_cmp_ge_f32 with the free |src|
// modifier directly on the raw float4 registers.
//
// Exact K-th largest via BRACKET BISECTION on abs bit patterns (== float order
// for positive finite floats): maintain lo (count>=K) / hi (count<K); probes
// warm-start near the expected K-th value (~1.648 for N(0,1), k/n=0.1) and
// ladder outward. Every bracket update is backed by an exact count, so the
// result is exact for any (finite) input; when the bracket closes to
// hi==lo+1, lo IS the exact K-th pattern and boundary ties are resolved by
// lowest-global-index ranking (matches lax.top_k stability).

constexpr int D_DIM = 2048;
constexpr int K_SEL = 204;     // int(2048 * 0.1)
constexpr int NT    = 256;     // 4 waves/block
constexpr int RPW   = 2;       // rows per wave (pipelined)

typedef float f32x4 __attribute__((ext_vector_type(4)));

// Full-wave64 integer sum via DPP; returns total (uniform, via readlane 63).
__device__ __forceinline__ int dpp_reduce_add(int x) {
    x += __builtin_amdgcn_update_dpp(0, x, 0x111, 0xF, 0xF, true);  // row_shr:1
    x += __builtin_amdgcn_update_dpp(0, x, 0x112, 0xF, 0xF, true);  // row_shr:2
    x += __builtin_amdgcn_update_dpp(0, x, 0x114, 0xF, 0xF, true);  // row_shr:4
    x += __builtin_amdgcn_update_dpp(0, x, 0x118, 0xF, 0xF, true);  // row_shr:8
    x += __builtin_amdgcn_update_dpp(0, x, 0x142, 0xA, 0xF, false); // row_bcast:15
    x += __builtin_amdgcn_update_dpp(0, x, 0x143, 0xC, 0xF, false); // row_bcast:31
    return __builtin_amdgcn_readlane(x, 63);
}

// Exact wave-wide count of elements with |value| >= t (t > 0, finite data).
__device__ __forceinline__ int wave_count_ge(const float4 (&f)[8], float t) {
    int c0 = 0, c1 = 0, c2 = 0, c3 = 0;
#pragma unroll
    for (int b = 0; b < 8; ++b) {
        c0 += (__builtin_fabsf(f[b].x) >= t) ? 1 : 0;
        c1 += (__builtin_fabsf(f[b].y) >= t) ? 1 : 0;
        c2 += (__builtin_fabsf(f[b].z) >= t) ? 1 : 0;
        c3 += (__builtin_fabsf(f[b].w) >= t) ? 1 : 0;
    }
    return dpp_reduce_add((c0 + c1) + (c2 + c3));
}

__device__ __forceinline__ void process_row(const float4 (&f)[8],
                                            float* __restrict__ outr,
                                            const int lane) {
    const float scale = 2048.0f / 204.0f;

    // Bracket invariant: count(>= lo) >= K > count(>= hi)  (on abs patterns).
    unsigned lo = 0u, hi = 0x80000000u;
    unsigned thr = 0u;
    bool done = false;

    // ---- Warm-start probe ladder (speed heuristic only; exact regardless) --
    {
        const int c = wave_count_ge(f, 1.6484375f);              // 0x3FD30000
        if (c == K_SEL) { thr = 0x3FD30000u; done = true; }
        else if (c > K_SEL) lo = 0x3FD30000u; else hi = 0x3FD30000u;
    }
    if (!done) {
        const unsigned p2 = (lo != 0u) ? 0x3FD60000u             // 1.671875
                                       : 0x3FD00000u;            // 1.625
        const int c = wave_count_ge(f, __uint_as_float(p2));
        if (c == K_SEL) { thr = p2; done = true; }
        else if (c > K_SEL) lo = p2; else hi = p2;
    }
    if (!done) {
        unsigned p3 = 0u;
        if (hi == 0x80000000u)      p3 = 0x3FE00000u;            // 1.75 (cap)
        else if (lo == 0u)          p3 = 0x3FC80000u;            // 1.5625 (floor)
        if (p3 != 0u) {
            const int c = wave_count_ge(f, __uint_as_float(p3));
            if (c == K_SEL) { thr = p3; done = true; }
            else if (c > K_SEL) lo = p3; else hi = p3;
        }
    }
    if (!done && lo == 0u) {   // very rare: K-th below 1.5625
        const int c = wave_count_ge(f, 1.0f);                    // 0x3F800000
        if (c == K_SEL) { thr = 0x3F800000u; done = true; }
        else if (c > K_SEL) lo = 0x3F800000u; else hi = 0x3F800000u;
    }

    // ---- Integer bisection of the bracket; early exit at exact count K. ----
#pragma unroll 1
    while (!done && (hi - lo) > 1u) {
        const unsigned mid = (lo + hi) >> 1;   // lo < mid < hi guaranteed
        const int c = wave_count_ge(f, __uint_as_float(mid));
        if (c == K_SEL) { thr = mid; done = true; }
        else if (c > K_SEL) lo = mid; else hi = mid;
    }

    f32x4* op = reinterpret_cast<f32x4*>(outr);

    if (done) {
        // Exact top-K set == {|x| >= thr}; no tie handling needed.
        const float tf = __uint_as_float(thr);
#pragma unroll
        for (int b = 0; b < 8; ++b) {
            f32x4 w;
            w.x = (__builtin_fabsf(f[b].x) >= tf) ? f[b].x * scale : 0.0f;
            w.y = (__builtin_fabsf(f[b].y) >= tf) ? f[b].y * scale : 0.0f;
            w.z = (__builtin_fabsf(f[b].z) >= tf) ? f[b].z * scale : 0.0f;
            w.w = (__builtin_fabsf(f[b].w) >= tf) ? f[b].w * scale : 0.0f;
            __builtin_nontemporal_store(w, op + b * 64 + lane);
        }
        return;
    }

    // Bracket closed: lo is the exact K-th largest pattern
    // (count(>=lo) > K since lo never hit count==K, count(>lo)=count(>=hi)<K).
    const float Tf = __uint_as_float(lo);
    int ge_pack = 0;
#pragma unroll
    for (int b = 0; b < 8; ++b) {
        ge_pack += (__builtin_fabsf(f[b].x) > Tf) ? 1 : 0;
        ge_pack += (__builtin_fabsf(f[b].y) > Tf) ? 1 : 0;
        ge_pack += (__builtin_fabsf(f[b].z) > Tf) ? 1 : 0;
        ge_pack += (__builtin_fabsf(f[b].w) > Tf) ? 1 : 0;
        ge_pack += (__builtin_fabsf(f[b].x) == Tf) ? (1 << 16) : 0;
        ge_pack += (__builtin_fabsf(f[b].y) == Tf) ? (1 << 16) : 0;
        ge_pack += (__builtin_fabsf(f[b].z) == Tf) ? (1 << 16) : 0;
        ge_pack += (__builtin_fabsf(f[b].w) == Tf) ? (1 << 16) : 0;
    }
    const int tot = dpp_reduce_add(ge_pack);
    const int cnt_gt = tot & 0xFFFF;
    const int neq = tot >> 16;
    const int r = K_SEL - cnt_gt;   // equals to keep (1 <= r <= neq)

    if (neq == r) {
#pragma unroll
        for (int b = 0; b < 8; ++b) {
            f32x4 w;
            w.x = (__builtin_fabsf(f[b].x) >= Tf) ? f[b].x * scale : 0.0f;
            w.y = (__builtin_fabsf(f[b].y) >= Tf) ? f[b].y * scale : 0.0f;
            w.z = (__builtin_fabsf(f[b].z) >= Tf) ? f[b].z * scale : 0.0f;
            w.w = (__builtin_fabsf(f[b].w) >= Tf) ? f[b].w * scale : 0.0f;
            __builtin_nontemporal_store(w, op + b * 64 + lane);
        }
        return;
    }

    // Rare: among ==T keep the r with lowest global index
    // (matches lax.top_k stability). Rank via equality ballots.
    // Element (b, lane, e): global index = 256*b + 4*lane + e.
    const unsigned long long lt = (lane == 0) ? 0ull : (~0ull >> (64 - lane));
    int base = 0;  // equals in blocks b' < b
    for (int b = 0; b < 8; ++b) {
        const float fe[4] = { f[b].x, f[b].y, f[b].z, f[b].w };
        unsigned long long m[4];
#pragma unroll
        for (int e = 0; e < 4; ++e) m[e] = __ballot(__builtin_fabsf(fe[e]) == Tf);
        int cm = 0;  // equals in this block from lanes < lane
#pragma unroll
        for (int e = 0; e < 4; ++e) cm += __popcll(m[e] & lt);
        f32x4 w;
        float wv[4];
        int partial = 0;  // equals: same lane, e' < e
#pragma unroll
        for (int e = 0; e < 4; ++e) {
            const int rank = base + cm + partial;
            const bool eq = (__builtin_fabsf(fe[e]) == Tf);
            const bool sel = (__builtin_fabsf(fe[e]) > Tf) || (eq && rank < r);
            wv[e] = sel ? fe[e] * scale : 0.0f;
            partial += (int)((m[e] >> lane) & 1ull);
        }
        w.x = wv[0]; w.y = wv[1]; w.z = wv[2]; w.w = wv[3];
        __builtin_nontemporal_store(w, op + b * 64 + lane);
#pragma unroll
        for (int e = 0; e < 4; ++e) base += __popcll(m[e]);
    }
}

__global__ __launch_bounds__(NT) void sparse_topk_kernel(const float* __restrict__ x,
                                                         float* __restrict__ out) {
    const int wave = threadIdx.x >> 6;
    const int lane = threadIdx.x & 63;
    const long long gw = (long long)blockIdx.x * 4 + wave;   // global wave id
    const long long r0 = gw * RPW;

    const float4* xp0 = reinterpret_cast<const float4*>(x + r0 * D_DIM);
    const float4* xp1 = reinterpret_cast<const float4*>(x + (r0 + 1) * D_DIM);

    // Issue ALL 16 loads up-front: row B's loads stay outstanding (compiler
    // waits only vmcnt(8) before touching row A) and complete for free under
    // row A's ~2000-cycle search + store.
    float4 fA[8], fB[8];
#pragma unroll
    for (int b = 0; b < 8; ++b) fA[b] = xp0[b * 64 + lane];
#pragma unroll
    for (int b = 0; b < 8; ++b) fB[b] = xp1[b * 64 + lane];

    process_row(fA, out + r0 * D_DIM, lane);
    process_row(fB, out + (r0 + 1) * D_DIM, lane);
}

extern "C" void kernel_launch(void* const* d_in, const int* in_sizes, int n_in,
                              void* d_out, int out_size, void* d_ws, size_t ws_size,
                              hipStream_t stream) {
    const float* x = (const float*)d_in[0];
    float* out = (float*)d_out;
    const int rows = in_sizes[0] / D_DIM;            // 16384
    sparse_topk_kernel<<<rows / (4 * RPW), NT, 0, stream>>>(x, out);
}

// Round 4
// 239.624 us; speedup vs baseline: 1.0106x; 1.0106x over previous
//
#include <hip/hip_runtime.h>

// SparseActivation: per row of D=2048 fp32, keep top K=204 by |x|, scale by D/K.
// One WAVE per 4 rows, register-double-buffered software pipeline:
//   load A<-row0, load B<-row1, [SB0],
//   process(A,row0), load A<-row2, [SB0],
//   process(B,row1), load B<-row3, [SB0],
//   process(A,row2), process(B,row3)
// Each row's ~900-cycle HBM latency hides under the previous row's ~1500-cycle
// search. __builtin_amdgcn_sched_barrier(0) pins every load batch ABOVE the
// following search — round-3 evidence (VGPR_Count stuck at 44) proved the
// scheduler otherwise sinks the prefetch loads to cut register pressure,
// silently deleting the pipeline.
//
// Search: exact K-th largest via BRACKET BISECTION on |x| (float compare with
// free |src| modifier; abs-pattern order == float order for finite floats).
// Warm-start probes near the expected K-th value (~1.648 for N(0,1), k/n=0.1),
// ladder outward; every bracket update is backed by an exact count, so the
// result is exact for ANY finite input. When the bracket closes to hi==lo+1,
// lo IS the exact K-th pattern; boundary ties resolved by lowest-global-index
// ranking (matches lax.top_k stability).

constexpr int D_DIM = 2048;
constexpr int K_SEL = 204;     // int(2048 * 0.1)
constexpr int NT    = 256;     // 4 waves/block
constexpr int RPW   = 4;       // rows per wave (pipelined)

typedef float f32x4 __attribute__((ext_vector_type(4)));

// Full-wave64 integer sum via DPP; returns total (uniform, via readlane 63).
__device__ __forceinline__ int dpp_reduce_add(int x) {
    x += __builtin_amdgcn_update_dpp(0, x, 0x111, 0xF, 0xF, true);  // row_shr:1
    x += __builtin_amdgcn_update_dpp(0, x, 0x112, 0xF, 0xF, true);  // row_shr:2
    x += __builtin_amdgcn_update_dpp(0, x, 0x114, 0xF, 0xF, true);  // row_shr:4
    x += __builtin_amdgcn_update_dpp(0, x, 0x118, 0xF, 0xF, true);  // row_shr:8
    x += __builtin_amdgcn_update_dpp(0, x, 0x142, 0xA, 0xF, false); // row_bcast:15
    x += __builtin_amdgcn_update_dpp(0, x, 0x143, 0xC, 0xF, false); // row_bcast:31
    return __builtin_amdgcn_readlane(x, 63);
}

// Exact wave-wide count of elements with |value| >= t (t > 0, finite data).
__device__ __forceinline__ int wave_count_ge(const float4 (&f)[8], float t) {
    int c0 = 0, c1 = 0, c2 = 0, c3 = 0;
#pragma unroll
    for (int b = 0; b < 8; ++b) {
        c0 += (__builtin_fabsf(f[b].x) >= t) ? 1 : 0;
        c1 += (__builtin_fabsf(f[b].y) >= t) ? 1 : 0;
        c2 += (__builtin_fabsf(f[b].z) >= t) ? 1 : 0;
        c3 += (__builtin_fabsf(f[b].w) >= t) ? 1 : 0;
    }
    return dpp_reduce_add((c0 + c1) + (c2 + c3));
}

__device__ __forceinline__ void process_row(const float4 (&f)[8],
                                            float* __restrict__ outr,
                                            const int lane) {
    const float scale = 2048.0f / 204.0f;

    // Bracket invariant: count(>= lo) >= K > count(>= hi)  (on abs patterns).
    unsigned lo = 0u, hi = 0x80000000u;
    unsigned thr = 0u;
    bool done = false;

    // ---- Warm-start probe ladder (speed heuristic only; exact regardless) --
    {
        const int c = wave_count_ge(f, 1.6484375f);              // 0x3FD30000
        if (c == K_SEL) { thr = 0x3FD30000u; done = true; }
        else if (c > K_SEL) lo = 0x3FD30000u; else hi = 0x3FD30000u;
    }
    if (!done) {
        const unsigned p2 = (lo != 0u) ? 0x3FD60000u             // 1.671875
                                       : 0x3FD00000u;            // 1.625
        const int c = wave_count_ge(f, __uint_as_float(p2));
        if (c == K_SEL) { thr = p2; done = true; }
        else if (c > K_SEL) lo = p2; else hi = p2;
    }
    if (!done) {
        unsigned p3 = 0u;
        if (hi == 0x80000000u)      p3 = 0x3FE00000u;            // 1.75 (cap)
        else if (lo == 0u)          p3 = 0x3FC80000u;            // 1.5625 (floor)
        if (p3 != 0u) {
            const int c = wave_count_ge(f, __uint_as_float(p3));
            if (c == K_SEL) { thr = p3; done = true; }
            else if (c > K_SEL) lo = p3; else hi = p3;
        }
    }
    if (!done && lo == 0u) {   // very rare: K-th below 1.5625
        const int c = wave_count_ge(f, 1.0f);                    // 0x3F800000
        if (c == K_SEL) { thr = 0x3F800000u; done = true; }
        else if (c > K_SEL) lo = 0x3F800000u; else hi = 0x3F800000u;
    }

    // ---- Integer bisection of the bracket; early exit at exact count K. ----
#pragma unroll 1
    while (!done && (hi - lo) > 1u) {
        const unsigned mid = (lo + hi) >> 1;   // lo < mid < hi guaranteed
        const int c = wave_count_ge(f, __uint_as_float(mid));
        if (c == K_SEL) { thr = mid; done = true; }
        else if (c > K_SEL) lo = mid; else hi = mid;
    }

    f32x4* op = reinterpret_cast<f32x4*>(outr);

    if (done) {
        // Exact top-K set == {|x| >= thr}; no tie handling needed.
        const float tf = __uint_as_float(thr);
#pragma unroll
        for (int b = 0; b < 8; ++b) {
            f32x4 w;
            w.x = (__builtin_fabsf(f[b].x) >= tf) ? f[b].x * scale : 0.0f;
            w.y = (__builtin_fabsf(f[b].y) >= tf) ? f[b].y * scale : 0.0f;
            w.z = (__builtin_fabsf(f[b].z) >= tf) ? f[b].z * scale : 0.0f;
            w.w = (__builtin_fabsf(f[b].w) >= tf) ? f[b].w * scale : 0.0f;
            __builtin_nontemporal_store(w, op + b * 64 + lane);
        }
        return;
    }

    // Bracket closed: lo is the exact K-th largest pattern
    // (count(>=lo) > K since lo never hit count==K, count(>lo)=count(>=hi)<K).
    const float Tf = __uint_as_float(lo);
    int ge_pack = 0;
#pragma unroll
    for (int b = 0; b < 8; ++b) {
        ge_pack += (__builtin_fabsf(f[b].x) > Tf) ? 1 : 0;
        ge_pack += (__builtin_fabsf(f[b].y) > Tf) ? 1 : 0;
        ge_pack += (__builtin_fabsf(f[b].z) > Tf) ? 1 : 0;
        ge_pack += (__builtin_fabsf(f[b].w) > Tf) ? 1 : 0;
        ge_pack += (__builtin_fabsf(f[b].x) == Tf) ? (1 << 16) : 0;
        ge_pack += (__builtin_fabsf(f[b].y) == Tf) ? (1 << 16) : 0;
        ge_pack += (__builtin_fabsf(f[b].z) == Tf) ? (1 << 16) : 0;
        ge_pack += (__builtin_fabsf(f[b].w) == Tf) ? (1 << 16) : 0;
    }
    const int tot = dpp_reduce_add(ge_pack);
    const int cnt_gt = tot & 0xFFFF;
    const int neq = tot >> 16;
    const int r = K_SEL - cnt_gt;   // equals to keep (1 <= r <= neq)

    if (neq == r) {
#pragma unroll
        for (int b = 0; b < 8; ++b) {
            f32x4 w;
            w.x = (__builtin_fabsf(f[b].x) >= Tf) ? f[b].x * scale : 0.0f;
            w.y = (__builtin_fabsf(f[b].y) >= Tf) ? f[b].y * scale : 0.0f;
            w.z = (__builtin_fabsf(f[b].z) >= Tf) ? f[b].z * scale : 0.0f;
            w.w = (__builtin_fabsf(f[b].w) >= Tf) ? f[b].w * scale : 0.0f;
            __builtin_nontemporal_store(w, op + b * 64 + lane);
        }
        return;
    }

    // Rare: among ==T keep the r with lowest global index
    // (matches lax.top_k stability). Rank via equality ballots.
    // Element (b, lane, e): global index = 256*b + 4*lane + e.
    const unsigned long long lt = (lane == 0) ? 0ull : (~0ull >> (64 - lane));
    int base = 0;  // equals in blocks b' < b
    for (int b = 0; b < 8; ++b) {
        const float fe[4] = { f[b].x, f[b].y, f[b].z, f[b].w };
        unsigned long long m[4];
#pragma unroll
        for (int e = 0; e < 4; ++e) m[e] = __ballot(__builtin_fabsf(fe[e]) == Tf);
        int cm = 0;  // equals in this block from lanes < lane
#pragma unroll
        for (int e = 0; e < 4; ++e) cm += __popcll(m[e] & lt);
        f32x4 w;
        float wv[4];
        int partial = 0;  // equals: same lane, e' < e
#pragma unroll
        for (int e = 0; e < 4; ++e) {
            const int rank = base + cm + partial;
            const bool eq = (__builtin_fabsf(fe[e]) == Tf);
            const bool sel = (__builtin_fabsf(fe[e]) > Tf) || (eq && rank < r);
            wv[e] = sel ? fe[e] * scale : 0.0f;
            partial += (int)((m[e] >> lane) & 1ull);
        }
        w.x = wv[0]; w.y = wv[1]; w.z = wv[2]; w.w = wv[3];
        __builtin_nontemporal_store(w, op + b * 64 + lane);
#pragma unroll
        for (int e = 0; e < 4; ++e) base += __popcll(m[e]);
    }
}

__global__ __launch_bounds__(NT) void sparse_topk_kernel(const float* __restrict__ x,
                                                         float* __restrict__ out) {
    const int wave = threadIdx.x >> 6;
    const int lane = threadIdx.x & 63;
    const long long gw = (long long)blockIdx.x * 4 + wave;   // global wave id
    const long long r0 = gw * RPW;

    // Row q of this wave starts at float4 offset q*512.
    const f32x4* xp = reinterpret_cast<const f32x4*>(x + r0 * D_DIM);
    float* outr = out + r0 * D_DIM;

    float4 A[8], B[8];

    // Prologue: rows 0 and 1 in flight together (first use waits vmcnt(8)).
#pragma unroll
    for (int b = 0; b < 8; ++b) {
        const f32x4 t = xp[b * 64 + lane];
        A[b] = make_float4(t.x, t.y, t.z, t.w);
    }
#pragma unroll
    for (int b = 0; b < 8; ++b) {
        const f32x4 t = xp[512 + b * 64 + lane];
        B[b] = make_float4(t.x, t.y, t.z, t.w);
    }
    __builtin_amdgcn_sched_barrier(0);   // loads may NOT sink below here

    process_row(A, outr, lane);                         // row 0
#pragma unroll
    for (int b = 0; b < 8; ++b) {                       // prefetch row 2 -> A
        const f32x4 t = xp[1024 + b * 64 + lane];
        A[b] = make_float4(t.x, t.y, t.z, t.w);
    }
    __builtin_amdgcn_sched_barrier(0);

    process_row(B, outr + D_DIM, lane);                 // row 1
#pragma unroll
    for (int b = 0; b < 8; ++b) {                       // prefetch row 3 -> B
        const f32x4 t = xp[1536 + b * 64 + lane];
        B[b] = make_float4(t.x, t.y, t.z, t.w);
    }
    __builtin_amdgcn_sched_barrier(0);

    process_row(A, outr + 2 * D_DIM, lane);             // row 2
    process_row(B, outr + 3 * D_DIM, lane);             // row 3
}

extern "C" void kernel_launch(void* const* d_in, const int* in_sizes, int n_in,
                              void* d_out, int out_size, void* d_ws, size_t ws_size,
                              hipStream_t stream) {
    const float* x = (const float*)d_in[0];
    float* out = (float*)d_out;
    const int rows = in_sizes[0] / D_DIM;            // 16384
    sparse_topk_kernel<<<rows / (4 * RPW), NT, 0, stream>>>(x, out);
}

// Round 6
// 236.102 us; speedup vs baseline: 1.0257x; 1.0149x over previous
//
#include <hip/hip_runtime.h>

// SparseActivation: per row of D=2048 fp32, keep top K=204 by |x|, scale D/K.
// One WAVE per 4 rows. The software pipeline is built from inline-asm VMEM so
// the compiler CANNOT delete it: rounds 3-4 proved (VGPR_Count pinned at 44)
// that C++-level prefetch loads get sunk below the branchy search by
// MachineSink, which __builtin_amdgcn_sched_barrier(0) does not fence.
// asm volatile global_load_dwordx4 outputs must be allocated at issue point,
// so row n+1's HBM latency (~900 cy) genuinely hides under row n's search
// (~2k cy). Counted s_waitcnt vmcnt(N) (+ sched_barrier(0), rule #18) gates
// each buffer's first use. vmcnt retires in issue order; compiler-generated
// stores between our asm ops only make counted waits stronger, never weaker.
//
// Op order (8 loads L / 8 stores S per row, source order pinned by "memory"):
//   L0 L1 [v8] srch0,S0 L2 [v16] srch1,S1 L3 [v16] srch2,S2 [v8] srch3,S3
// [v16] before srch1: ops after L1 = S0+L2 = 16 -> vmcnt(16) proves L1 done.
//
// Search: exact K-th largest via BRACKET BISECTION on |x| (float compare with
// free |src| modifier). Warm-start probes near the expected K-th value
// (~1.648 for N(0,1), k/n=0.1); every bracket update is backed by an exact
// count so the result is exact for ANY finite input. Bracket closed to
// hi==lo+1 => lo is the exact K-th pattern; boundary ties resolved by
// lowest-global-index ranking (matches lax.top_k stability).

constexpr int D_DIM = 2048;
constexpr int K_SEL = 204;     // int(2048 * 0.1)
constexpr int NT    = 256;     // 4 waves/block
constexpr int RPW   = 4;       // rows per wave (pipelined)

typedef float f32x4 __attribute__((ext_vector_type(4)));

// Pipeline-proof 16B load: output must be register-allocated at issue point.
__device__ __forceinline__ f32x4 gload16(const f32x4* p) {
    f32x4 r;
    asm volatile("global_load_dwordx4 %0, %1, off" : "=v"(r) : "v"(p) : "memory");
    return r;
}

// Counted wait + scheduler fence (rule #18: reg-only VALU can be hoisted past
// an inline-asm waitcnt despite the memory clobber; sched_barrier(0) stops it).
#define VMWAIT(n)                                                  \
    do {                                                           \
        asm volatile("s_waitcnt vmcnt(" #n ")" ::: "memory");      \
        __builtin_amdgcn_sched_barrier(0);                         \
    } while (0)

// Full-wave64 integer sum via DPP; returns total (uniform, via readlane 63).
__device__ __forceinline__ int dpp_reduce_add(int x) {
    x += __builtin_amdgcn_update_dpp(0, x, 0x111, 0xF, 0xF, true);  // row_shr:1
    x += __builtin_amdgcn_update_dpp(0, x, 0x112, 0xF, 0xF, true);  // row_shr:2
    x += __builtin_amdgcn_update_dpp(0, x, 0x114, 0xF, 0xF, true);  // row_shr:4
    x += __builtin_amdgcn_update_dpp(0, x, 0x118, 0xF, 0xF, true);  // row_shr:8
    x += __builtin_amdgcn_update_dpp(0, x, 0x142, 0xA, 0xF, false); // row_bcast:15
    x += __builtin_amdgcn_update_dpp(0, x, 0x143, 0xC, 0xF, false); // row_bcast:31
    return __builtin_amdgcn_readlane(x, 63);
}

// Exact wave-wide count of elements with |value| >= t (t > 0, finite data).
__device__ __forceinline__ int wave_count_ge(const f32x4 (&f)[8], float t) {
    int c0 = 0, c1 = 0, c2 = 0, c3 = 0;
#pragma unroll
    for (int b = 0; b < 8; ++b) {
        c0 += (__builtin_fabsf(f[b].x) >= t) ? 1 : 0;
        c1 += (__builtin_fabsf(f[b].y) >= t) ? 1 : 0;
        c2 += (__builtin_fabsf(f[b].z) >= t) ? 1 : 0;
        c3 += (__builtin_fabsf(f[b].w) >= t) ? 1 : 0;
    }
    return dpp_reduce_add((c0 + c1) + (c2 + c3));
}

__device__ __forceinline__ void process_row(const f32x4 (&f)[8],
                                            float* __restrict__ outr,
                                            const int lane) {
    const float scale = 2048.0f / 204.0f;

    // Bracket invariant: count(>= lo) >= K > count(>= hi)  (on abs patterns).
    unsigned lo = 0u, hi = 0x80000000u;
    unsigned thr = 0u;
    bool done = false;

    // ---- Warm-start probe ladder (speed heuristic only; exact regardless) --
    {
        const int c = wave_count_ge(f, 1.6484375f);              // 0x3FD30000
        if (c == K_SEL) { thr = 0x3FD30000u; done = true; }
        else if (c > K_SEL) lo = 0x3FD30000u; else hi = 0x3FD30000u;
    }
    if (!done) {
        const unsigned p2 = (lo != 0u) ? 0x3FD60000u             // 1.671875
                                       : 0x3FD00000u;            // 1.625
        const int c = wave_count_ge(f, __uint_as_float(p2));
        if (c == K_SEL) { thr = p2; done = true; }
        else if (c > K_SEL) lo = p2; else hi = p2;
    }
    if (!done) {
        unsigned p3 = 0u;
        if (hi == 0x80000000u)      p3 = 0x3FE00000u;            // 1.75 (cap)
        else if (lo == 0u)          p3 = 0x3FC80000u;            // 1.5625 (floor)
        if (p3 != 0u) {
            const int c = wave_count_ge(f, __uint_as_float(p3));
            if (c == K_SEL) { thr = p3; done = true; }
            else if (c > K_SEL) lo = p3; else hi = p3;
        }
    }
    if (!done && lo == 0u) {   // very rare: K-th below 1.5625
        const int c = wave_count_ge(f, 1.0f);                    // 0x3F800000
        if (c == K_SEL) { thr = 0x3F800000u; done = true; }
        else if (c > K_SEL) lo = 0x3F800000u; else hi = 0x3F800000u;
    }

    // ---- Integer bisection of the bracket; early exit at exact count K. ----
#pragma unroll 1
    while (!done && (hi - lo) > 1u) {
        const unsigned mid = (lo + hi) >> 1;   // lo < mid < hi guaranteed
        const int c = wave_count_ge(f, __uint_as_float(mid));
        if (c == K_SEL) { thr = mid; done = true; }
        else if (c > K_SEL) lo = mid; else hi = mid;
    }

    f32x4* op = reinterpret_cast<f32x4*>(outr);

    if (done) {
        // Exact top-K set == {|x| >= thr}; no tie handling needed.
        const float tf = __uint_as_float(thr);
#pragma unroll
        for (int b = 0; b < 8; ++b) {
            f32x4 w;
            w.x = (__builtin_fabsf(f[b].x) >= tf) ? f[b].x * scale : 0.0f;
            w.y = (__builtin_fabsf(f[b].y) >= tf) ? f[b].y * scale : 0.0f;
            w.z = (__builtin_fabsf(f[b].z) >= tf) ? f[b].z * scale : 0.0f;
            w.w = (__builtin_fabsf(f[b].w) >= tf) ? f[b].w * scale : 0.0f;
            __builtin_nontemporal_store(w, op + b * 64 + lane);
        }
        return;
    }

    // Bracket closed: lo is the exact K-th largest pattern
    // (count(>=lo) > K since lo never hit count==K, count(>lo)=count(>=hi)<K).
    const float Tf = __uint_as_float(lo);
    int ge_pack = 0;
#pragma unroll
    for (int b = 0; b < 8; ++b) {
        ge_pack += (__builtin_fabsf(f[b].x) > Tf) ? 1 : 0;
        ge_pack += (__builtin_fabsf(f[b].y) > Tf) ? 1 : 0;
        ge_pack += (__builtin_fabsf(f[b].z) > Tf) ? 1 : 0;
        ge_pack += (__builtin_fabsf(f[b].w) > Tf) ? 1 : 0;
        ge_pack += (__builtin_fabsf(f[b].x) == Tf) ? (1 << 16) : 0;
        ge_pack += (__builtin_fabsf(f[b].y) == Tf) ? (1 << 16) : 0;
        ge_pack += (__builtin_fabsf(f[b].z) == Tf) ? (1 << 16) : 0;
        ge_pack += (__builtin_fabsf(f[b].w) == Tf) ? (1 << 16) : 0;
    }
    const int tot = dpp_reduce_add(ge_pack);
    const int cnt_gt = tot & 0xFFFF;
    const int neq = tot >> 16;
    const int r = K_SEL - cnt_gt;   // equals to keep (1 <= r <= neq)

    if (neq == r) {
#pragma unroll
        for (int b = 0; b < 8; ++b) {
            f32x4 w;
            w.x = (__builtin_fabsf(f[b].x) >= Tf) ? f[b].x * scale : 0.0f;
            w.y = (__builtin_fabsf(f[b].y) >= Tf) ? f[b].y * scale : 0.0f;
            w.z = (__builtin_fabsf(f[b].z) >= Tf) ? f[b].z * scale : 0.0f;
            w.w = (__builtin_fabsf(f[b].w) >= Tf) ? f[b].w * scale : 0.0f;
            __builtin_nontemporal_store(w, op + b * 64 + lane);
        }
        return;
    }

    // Rare: among ==T keep the r with lowest global index
    // (matches lax.top_k stability). Rank via equality ballots.
    // Element (b, lane, e): global index = 256*b + 4*lane + e.
    const unsigned long long lt = (lane == 0) ? 0ull : (~0ull >> (64 - lane));
    int base = 0;  // equals in blocks b' < b
    for (int b = 0; b < 8; ++b) {
        const float fe[4] = { f[b].x, f[b].y, f[b].z, f[b].w };
        unsigned long long m[4];
#pragma unroll
        for (int e = 0; e < 4; ++e) m[e] = __ballot(__builtin_fabsf(fe[e]) == Tf);
        int cm = 0;  // equals in this block from lanes < lane
#pragma unroll
        for (int e = 0; e < 4; ++e) cm += __popcll(m[e] & lt);
        f32x4 w;
        float wv[4];
        int partial = 0;  // equals: same lane, e' < e
#pragma unroll
        for (int e = 0; e < 4; ++e) {
            const int rank = base + cm + partial;
            const bool eq = (__builtin_fabsf(fe[e]) == Tf);
            const bool sel = (__builtin_fabsf(fe[e]) > Tf) || (eq && rank < r);
            wv[e] = sel ? fe[e] * scale : 0.0f;
            partial += (int)((m[e] >> lane) & 1ull);
        }
        w.x = wv[0]; w.y = wv[1]; w.z = wv[2]; w.w = wv[3];
        __builtin_nontemporal_store(w, op + b * 64 + lane);
#pragma unroll
        for (int e = 0; e < 4; ++e) base += __popcll(m[e]);
    }
}

__global__ __launch_bounds__(NT) void sparse_topk_kernel(const float* __restrict__ x,
                                                         float* __restrict__ out) {
    const int wave = threadIdx.x >> 6;
    const int lane = threadIdx.x & 63;
    const long long gw = (long long)blockIdx.x * 4 + wave;   // global wave id
    const long long r0 = gw * RPW;

    const f32x4* xp = reinterpret_cast<const f32x4*>(x + r0 * D_DIM);
    float* outr = out + r0 * D_DIM;

    f32x4 A[8], B[8];

    // L0, L1: rows 0 and 1 in flight together.
#pragma unroll
    for (int b = 0; b < 8; ++b) A[b] = gload16(xp + b * 64 + lane);
#pragma unroll
    for (int b = 0; b < 8; ++b) B[b] = gload16(xp + 512 + b * 64 + lane);

    VMWAIT(8);                                   // A (row 0) ready; L1 in flight
    process_row(A, outr, lane);                  // srch0 + S0 (8 stores)
#pragma unroll
    for (int b = 0; b < 8; ++b) A[b] = gload16(xp + 1024 + b * 64 + lane);  // L2

    VMWAIT(16);                                  // ops after L1 = S0+L2 = 16
    process_row(B, outr + D_DIM, lane);          // srch1 + S1
#pragma unroll
    for (int b = 0; b < 8; ++b) B[b] = gload16(xp + 1536 + b * 64 + lane);  // L3

    VMWAIT(16);                                  // ops after L2 = S1+L3 = 16
    process_row(A, outr + 2 * D_DIM, lane);      // srch2 + S2

    VMWAIT(8);                                   // ops after L3 = S2 = 8
    process_row(B, outr + 3 * D_DIM, lane);      // srch3 + S3
}

extern "C" void kernel_launch(void* const* d_in, const int* in_sizes, int n_in,
                              void* d_out, int out_size, void* d_ws, size_t ws_size,
                              hipStream_t stream) {
    const float* x = (const float*)d_in[0];
    float* out = (float*)d_out;
    const int rows = in_sizes[0] / D_DIM;            // 16384
    sparse_topk_kernel<<<rows / (4 * RPW), NT, 0, stream>>>(x, out);
}